// Round 12
// baseline (381.320 us; speedup 1.0000x reference)
//
#include <hip/hip_runtime.h>
#include <math.h>

#define TSEQ   2048
#define BB     2
#define DMODEL 1024
#define NHEAD  16
#define DHEAD  64
#define MROWS  (TSEQ * BB)   // 4096

typedef __attribute__((ext_vector_type(8))) _Float16 half8;
typedef __attribute__((ext_vector_type(4))) float    floatx4;
typedef unsigned short u16;
typedef unsigned int   u32;

#define QSCL 11.5415603f   /* 8 * log2(e): Q pre-scale -> exp2-domain scores */
#define MSK  1442695.0f    /* 1e6 * log2(e) */

__device__ __forceinline__ u16 f2h(float f) {
    union { _Float16 h; u16 u; } cv;
    cv.h = (_Float16)f;
    return cv.u;
}

// packed fp32x2 -> fp16x2 (round-to-zero) as u32
__device__ __forceinline__ u32 pkrtz(float a, float b) {
    typedef __attribute__((ext_vector_type(2))) __fp16 fp16x2;
    union { fp16x2 h; u32 u; } cv;
    cv.h = __builtin_amdgcn_cvt_pkrtz(a, b);
    return cv.u;
}

__device__ __forceinline__ void async_cp16(const u16* g, u16* l) {
    __builtin_amdgcn_global_load_lds(
        (const __attribute__((address_space(1))) unsigned int*)g,
        (__attribute__((address_space(3))) unsigned int*)l, 16, 0, 0);
}

// ---------------------------------------------------------------------------
// one-launch fp32 -> fp16 cast of x, qkv_w, out_w
// ---------------------------------------------------------------------------
__global__ __launch_bounds__(256)
void cast3_f32_f16(const float* __restrict__ a, u16* __restrict__ oa,
                   const float* __restrict__ b, u16* __restrict__ ob,
                   const float* __restrict__ c, u16* __restrict__ oc)
{
    int i = blockIdx.x * 256 + threadIdx.x;
    const float* src; u16* dst; int off;
    if (i < 1048576)      { src = a; dst = oa; off = 0; }
    else if (i < 1835008) { src = b; dst = ob; off = 1048576; }
    else                  { src = c; dst = oc; off = 1835008; }
    int j = i - off;
    float4 v = ((const float4*)src)[j];
    ushort4 o;
    o.x = f2h(v.x); o.y = f2h(v.y); o.z = f2h(v.z); o.w = f2h(v.w);
    ((ushort4*)dst)[j] = o;
}

// ---------------------------------------------------------------------------
// QKV GEMM: 128x128 tile, BK=64, 8 waves; per-wave profile = proven 128x64
// kernel (acc[2][4], 16 MFMA/K-step); 24 waves/CU.  (round-11: 46.0 us)
// ---------------------------------------------------------------------------
__global__ __launch_bounds__(512)
void gemm_qkv(const u16* __restrict__ A, const u16* __restrict__ W,
              const float* __restrict__ bias,
              u16* __restrict__ Qo, u16* __restrict__ Ko, u16* __restrict__ Vo,
              int M, int N, int K)
{
    __shared__ __align__(16) u16 As[128][64];
    __shared__ __align__(16) u16 Bs[128][64];

    const int tid  = threadIdx.x;
    const int lane = tid & 63;
    const int wv   = tid >> 6;               // 0..7
    const int wr   = wv >> 1;                // 0..3: 32-row band
    const int wc   = wv & 1;                 // 0..1: 64-col half
    const int ln   = lane & 15, lh = lane >> 4;
    const int m0   = blockIdx.y * 128;
    const int n0   = blockIdx.x * 128;

    const int c = n0 >> 10;                  // 0,1,2 = q,k,v (block-uniform)
    const bool vmode = (c == 2);             // normal orientation

    const floatx4 zero4 = {0.0f, 0.0f, 0.0f, 0.0f};
    floatx4 acc[2][4];
#pragma unroll
    for (int i = 0; i < 2; ++i)
#pragma unroll
        for (int j = 0; j < 4; ++j) acc[i][j] = zero4;

    for (int k0 = 0; k0 < K; k0 += 64) {
        __syncthreads();
#pragma unroll
        for (int t = 0; t < 2; ++t) {
            const int u    = t * 512 + tid;
            const int row  = u >> 3;
            const int slot = u & 7;
            const int g    = slot ^ (row & 7);
            async_cp16(A + (size_t)(m0 + row) * K + k0 + g * 8, &As[row][slot * 8]);
            async_cp16(W + (size_t)(n0 + row) * K + k0 + g * 8, &Bs[row][slot * 8]);
        }
        __syncthreads();

#pragma unroll
        for (int ks = 0; ks < 2; ++ks) {
            half8 xf[2], wf[4];
#pragma unroll
            for (int i = 0; i < 2; ++i) {
                const int row = wr * 32 + i * 16 + ln;
                xf[i] = *(const half8*)&As[row][(((ks << 2) | lh) ^ (row & 7)) * 8];
            }
#pragma unroll
            for (int j = 0; j < 4; ++j) {
                const int row = wc * 64 + j * 16 + ln;
                wf[j] = *(const half8*)&Bs[row][(((ks << 2) | lh) ^ (row & 7)) * 8];
            }
            if (vmode) {
#pragma unroll
                for (int i = 0; i < 2; ++i)
#pragma unroll
                    for (int j = 0; j < 4; ++j)
                        acc[i][j] = __builtin_amdgcn_mfma_f32_16x16x32_f16(xf[i], wf[j], acc[i][j], 0, 0, 0);
            } else {
#pragma unroll
                for (int i = 0; i < 2; ++i)
#pragma unroll
                    for (int j = 0; j < 4; ++j)
                        acc[i][j] = __builtin_amdgcn_mfma_f32_16x16x32_f16(wf[j], xf[i], acc[i][j], 0, 0, 0);
            }
        }
    }

    if (!vmode) {
        const float scl = (c == 0) ? QSCL : 1.0f;
        u16* dst = (c == 0) ? Qo : Ko;
#pragma unroll
        for (int j = 0; j < 4; ++j) {
            const int nb = n0 + wc * 64 + j * 16 + lh * 4;
            const float4 b4 = *(const float4*)&bias[nb];
            const int h  = (nb >> 6) & 15;
            const int d0 = nb & 63;
#pragma unroll
            for (int i = 0; i < 2; ++i) {
                const int tok = m0 + wr * 32 + i * 16 + ln;
                const int t = tok >> 1, b = tok & 1;
                uint2 pk;
                pk.x = pkrtz((acc[i][j][0] + b4.x) * scl, (acc[i][j][1] + b4.y) * scl);
                pk.y = pkrtz((acc[i][j][2] + b4.z) * scl, (acc[i][j][3] + b4.w) * scl);
                *(uint2*)&dst[(((size_t)b * NHEAD + h) * TSEQ + t) * DHEAD + d0] = pk;
            }
        }
    } else {
#pragma unroll
        for (int j = 0; j < 4; ++j) {
            const int col = n0 + wc * 64 + j * 16 + ln;
            const float bc = bias[col];
            const int h = (col >> 6) & 15;
            const int d = col & 63;
#pragma unroll
            for (int i = 0; i < 2; ++i) {
                const int mb = m0 + wr * 32 + i * 16 + lh * 4;
                const int t0 = mb >> 1;
                const u32 e0 = pkrtz(acc[i][j][0] + bc, acc[i][j][2] + bc);  // b=0
                const u32 e1 = pkrtz(acc[i][j][1] + bc, acc[i][j][3] + bc);  // b=1
                *(u32*)&Vo[(((size_t)0 * NHEAD + h) * DHEAD + d) * TSEQ + t0] = e0;
                *(u32*)&Vo[(((size_t)1 * NHEAD + h) * DHEAD + d) * TSEQ + t0] = e1;
            }
        }
    }
}

// ---------------------------------------------------------------------------
// out-proj GEMM: 64x64 tile, BK=128; XCD swizzle. (round-8 verified ~26 us)
// ---------------------------------------------------------------------------
__global__ __launch_bounds__(256)
void gemm_out64(const u16* __restrict__ A, const u16* __restrict__ W,
                const float* __restrict__ bias, float* __restrict__ Cout,
                int M, int N, int K)
{
    __shared__ __align__(16) u16 As[64][128];
    __shared__ __align__(16) u16 Bs[64][128];

    const int tid  = threadIdx.x;
    const int lane = tid & 63;
    const int wv   = tid >> 6;
    const int ln   = lane & 15, lh = lane >> 4;

    const int bidlin = blockIdx.y * 16 + blockIdx.x;
    const int wg  = (bidlin & 7) * 128 + (bidlin >> 3);
    const int bx  = wg & 15, by = wg >> 4;
    const int m0  = by * 64;
    const int n0  = bx * 64;

    const floatx4 zero4 = {0.0f, 0.0f, 0.0f, 0.0f};
    floatx4 acc[4];
#pragma unroll
    for (int j = 0; j < 4; ++j) acc[j] = zero4;

    for (int k0 = 0; k0 < K; k0 += 128) {
        __syncthreads();
#pragma unroll
        for (int u = 0; u < 4; ++u) {
            const int idx  = u * 256 + tid;
            const int row  = idx >> 4;
            const int slot = idx & 15;
            const int g    = (slot & 8) | ((slot & 7) ^ (row & 7));
            async_cp16(A + (size_t)(m0 + row) * K + k0 + g * 8, &As[row][slot * 8]);
            async_cp16(W + (size_t)(n0 + row) * K + k0 + g * 8, &Bs[row][slot * 8]);
        }
        __syncthreads();

#pragma unroll
        for (int ks = 0; ks < 4; ++ks) {
            const int arow = wv * 16 + ln;
            half8 xf = *(const half8*)&As[arow][(((ks << 2) | lh) ^ (arow & 7)) * 8];
#pragma unroll
            for (int j = 0; j < 4; ++j) {
                const int row = j * 16 + ln;
                half8 wf = *(const half8*)&Bs[row][(((ks << 2) | lh) ^ (row & 7)) * 8];
                acc[j] = __builtin_amdgcn_mfma_f32_16x16x32_f16(wf, xf, acc[j], 0, 0, 0);
            }
        }
    }

#pragma unroll
    for (int j = 0; j < 4; ++j) {
        const int fb = n0 + j * 16 + lh * 4;
        const float4 b4 = *(const float4*)&bias[fb];
        const int tok = m0 + wv * 16 + ln;
        float4 v;
        v.x = acc[j][0] + b4.x;
        v.y = acc[j][1] + b4.y;
        v.z = acc[j][2] + b4.z;
        v.w = acc[j][3] + b4.w;
        *(float4*)&Cout[(size_t)tok * N + fb] = v;
    }
}

// ---------------------------------------------------------------------------
// SPLIT-K flash attention (round-12). Round-11 analysis: the old 1024-block
// grid was exact-residency with no backfill; CU time was pinned to the
// longest block's 32-iter serial path while avg occupancy decayed to ~29%
// (measured; matches the 8.25-waves/CU arithmetic). Now each (bh,qb) tile is
// computed by TWO blocks covering halves of its kb range (max 16 iters),
// each writing a normalized fp32 partial O + per-row (m,l). Grid 2048 ->
// 6 resident blocks/CU (LDS 24.6KB) + backfill queue; long tiles (qb=31)
// dispatched first. flash_merge recombines: w_s = l_s*2^(m_s-m)/sum.
// Keeps: swizzled LDS (0-conflict), defer-max, ones-frag l_i, setprio.
// ---------------------------------------------------------------------------
__global__ __launch_bounds__(256, 6)
void flash_f16(const u16* __restrict__ Q, const u16* __restrict__ K,
               const u16* __restrict__ Vt,
               float* __restrict__ Ou, float* __restrict__ Mp,
               float* __restrict__ Lp,
               const int* __restrict__ causal_p)
{
    // rows 0..63 = P; 64..127 = K; 128..191 = V^T   (24.6 KB, no pad)
    __shared__ __align__(16) u16 smem[192 * 64];
    u16 (* __restrict__ Ps)[64] = (u16(*)[64])smem;
    u16 (* __restrict__ Ks)[64] = (u16(*)[64])(smem + 64 * 64);
    u16 (* __restrict__ Vs)[64] = (u16(*)[64])(smem + 128 * 64);

    const int tid  = threadIdx.x;
    const int lane = tid & 63;
    const int wv   = tid >> 6;
    const int ln   = lane & 15, lh = lane >> 4;

    const int bid   = blockIdx.x;
    const int split = bid & 1;
    const int tile  = bid >> 1;
    const int bh    = tile & 31;                // b*16 + h
    const int qb    = 31 - (tile >> 5);         // descending: long tiles first

    const int causal = causal_p[0];
    const int n    = causal ? (qb + 1) : (TSEQ / 64);
    const int half = (n + 1) >> 1;
    const int kb_beg = split ? half : 0;
    const int kb_end = split ? n : half;        // exclusive; may be empty

    const u16* Qg = Q  + (size_t)bh * TSEQ * DHEAD;
    const u16* Kg = K  + (size_t)bh * TSEQ * DHEAD;
    const u16* Vg = Vt + (size_t)bh * DHEAD * TSEQ;

    const int lrow = tid >> 3;                  // 0..31
    const int lc8  = (tid & 7) * 8;             // global col (linear)
    const int lg8  = ((tid & 7) ^ (lrow & 7)) * 8;   // LDS col (swizzled)

    const int qr0   = wv * 16;
    const int qloc  = qr0 + ln;                 // this lane's q-row (local)
    const int s7    = ln & 7;                   // row&7 for all frag rows
    const int qglob = qb * 64 + qloc;

    // Q B-frags straight from global (read once)
    const half8 bQ0 = *(const half8*)(Qg + (size_t)qglob * DHEAD + lh * 8);
    const half8 bQ1 = *(const half8*)(Qg + (size_t)qglob * DHEAD + 32 + lh * 8);

    // ones B-frag: B[k][col] = (col==0) -> lanes with ln==0 hold 1.0
    const _Float16 ov = (_Float16)((ln == 0) ? 1.0f : 0.0f);
    const half8 ones = {ov, ov, ov, ov, ov, ov, ov, ov};

    const floatx4 zero4 = {0.0f, 0.0f, 0.0f, 0.0f};
    floatx4 o[4], o4;
#pragma unroll
    for (int j = 0; j < 4; ++j) o[j] = zero4;
    o4 = zero4;
    float m_i = -3.0e38f;

    // prologue: prefetch first K/V^T block of this split into regs
    const size_t kb0 = (size_t)kb_beg * 64;
    uint4 kreg0 = *(const uint4*)(Kg + (kb0 + lrow) * DHEAD + lc8);
    uint4 kreg1 = *(const uint4*)(Kg + (kb0 + lrow + 32) * DHEAD + lc8);
    uint4 vreg0 = *(const uint4*)(Vg + (size_t)lrow * TSEQ + kb0 + lc8);
    uint4 vreg1 = *(const uint4*)(Vg + (size_t)(lrow + 32) * TSEQ + kb0 + lc8);

    for (int kb = kb_beg; kb < kb_end; ++kb) {
        // stage prefetched regs -> LDS (swizzled dest; (lrow+32)&7 == lrow&7)
        *(uint4*)&Ks[lrow][lg8]      = kreg0;
        *(uint4*)&Ks[lrow + 32][lg8] = kreg1;
        *(uint4*)&Vs[lrow][lg8]      = vreg0;
        *(uint4*)&Vs[lrow + 32][lg8] = vreg1;
        __syncthreads();

        // prefetch next K/V^T block (hidden behind compute)
        if (kb + 1 < kb_end) {
            const size_t nk = (size_t)(kb + 1) * 64;
            kreg0 = *(const uint4*)(Kg + (nk + lrow) * DHEAD + lc8);
            kreg1 = *(const uint4*)(Kg + (nk + lrow + 32) * DHEAD + lc8);
            vreg0 = *(const uint4*)(Vg + (size_t)lrow * TSEQ + nk + lc8);
            vreg1 = *(const uint4*)(Vg + (size_t)(lrow + 32) * TSEQ + nk + lc8);
        }

        // S^T = K Q^T : s[j][r] = S[key = 16j+4lh+r][q = qloc]
        floatx4 s[4];
        __builtin_amdgcn_s_setprio(1);
#pragma unroll
        for (int j = 0; j < 4; ++j) {
            half8 aK0 = *(const half8*)&Ks[j * 16 + ln][(lh ^ s7) * 8];
            half8 aK1 = *(const half8*)&Ks[j * 16 + ln][((4 | lh) ^ s7) * 8];
            floatx4 z = zero4;
            z = __builtin_amdgcn_mfma_f32_16x16x32_f16(aK0, bQ0, z, 0, 0, 0);
            z = __builtin_amdgcn_mfma_f32_16x16x32_f16(aK1, bQ1, z, 0, 0, 0);
            s[j] = z;
        }
        __builtin_amdgcn_s_setprio(0);

        // V frags early: LDS latency hides under the softmax VALU burst
        half8 bV[8];
#pragma unroll
        for (int j = 0; j < 4; ++j) {
            bV[2 * j]     = *(const half8*)&Vs[j * 16 + ln][(lh ^ s7) * 8];
            bV[2 * j + 1] = *(const half8*)&Vs[j * 16 + ln][((4 | lh) ^ s7) * 8];
        }

        // causal mask: only the diagonal tile needs it
        if ((causal != 0) && (kb == qb)) {
#pragma unroll
            for (int j = 0; j < 4; ++j)
#pragma unroll
                for (int r = 0; r < 4; ++r)
                    if (kb * 64 + j * 16 + lh * 4 + r - kb * 64 > qloc) s[j][r] -= MSK;
        }

        // per-lane online max (one q-row per lane; reduce across lh groups)
        float mx = m_i;
#pragma unroll
        for (int j = 0; j < 4; ++j)
#pragma unroll
            for (int r = 0; r < 4; ++r) mx = fmaxf(mx, s[j][r]);
        mx = fmaxf(mx, __shfl_xor(mx, 16));
        mx = fmaxf(mx, __shfl_xor(mx, 32));

        // defer-max: rescale only when the max moved by >8 exp2-units
        if (!__all(mx <= m_i + 8.0f)) {
            const float alpha = exp2f(m_i - mx);
            m_i = mx;
            float a_r[4];
#pragma unroll
            for (int r = 0; r < 4; ++r) a_r[r] = __shfl(alpha, lh * 4 + r);
#pragma unroll
            for (int j = 0; j < 4; ++j)
#pragma unroll
                for (int r = 0; r < 4; ++r) o[j][r] *= a_r[r];
#pragma unroll
            for (int r = 0; r < 4; ++r) o4[r] *= a_r[r];
        }

        // P = exp2(s - m_i), packed to LDS (swizzled, same row-XOR)
#pragma unroll
        for (int j = 0; j < 4; ++j) {
            uint2 pk;
            pk.x = pkrtz(exp2f(s[j][0] - m_i), exp2f(s[j][1] - m_i));
            pk.y = pkrtz(exp2f(s[j][2] - m_i), exp2f(s[j][3] - m_i));
            *(uint2*)&Ps[qloc][(((2 * j + (lh >> 1)) ^ s7) * 8) + (lh & 1) * 4] = pk;
        }

        // O += P V ; o4 += P * ones (row-sums -> l_i recurrence for free)
        half8 aP0 = *(const half8*)&Ps[qloc][(lh ^ s7) * 8];
        half8 aP1 = *(const half8*)&Ps[qloc][((4 | lh) ^ s7) * 8];
        __builtin_amdgcn_s_setprio(1);
#pragma unroll
        for (int j = 0; j < 4; ++j) {
            o[j] = __builtin_amdgcn_mfma_f32_16x16x32_f16(aP0, bV[2 * j],     o[j], 0, 0, 0);
            o[j] = __builtin_amdgcn_mfma_f32_16x16x32_f16(aP1, bV[2 * j + 1], o[j], 0, 0, 0);
        }
        o4 = __builtin_amdgcn_mfma_f32_16x16x32_f16(aP0, ones, o4, 0, 0, 0);
        o4 = __builtin_amdgcn_mfma_f32_16x16x32_f16(aP1, ones, o4, 0, 0, 0);
        __builtin_amdgcn_s_setprio(0);

        __syncthreads();   // all reads of Ks/Vs/Ps done before next staging
    }

    // epilogue: write NORMALIZED fp32 partial O + per-row m, l.
    // o rows = q-local lh*4+r, cols d = 16j+ln. l of row 4lh'+r in o4[r] of
    // lane 16lh'; m of row qr0+t in lanes with ln==t.
    float* Obase = Ou + (size_t)bid * 4096;
#pragma unroll
    for (int r = 0; r < 4; ++r) {
        const float lr = __shfl(o4[r], lane & 48);
        const float il = (lr > 0.0f) ? 1.0f / lr : 0.0f;   // empty split -> 0
        const float mr = __shfl(m_i, lh * 4 + r);
        const int row = qr0 + lh * 4 + r;
        if (ln == 0) {
            Mp[(size_t)bid * 64 + row] = mr;
            Lp[(size_t)bid * 64 + row] = lr;
        }
#pragma unroll
        for (int j = 0; j < 4; ++j)
            Obase[row * 64 + j * 16 + ln] = o[j][r] * il;
    }
}

// ---------------------------------------------------------------------------
// merge the two split partials of each (bh,qb) tile into fp16 AV.
// w_s = l_s * 2^(m_s - m) / (l1*2^(m1-m) + l2*2^(m2-m)); O = w1*O1 + w2*O2.
// Empty split has l=0 -> weight 0 (its O is zeros). 42 MB traffic, BW-bound.
// ---------------------------------------------------------------------------
__global__ __launch_bounds__(256)
void flash_merge(const float* __restrict__ Ou, const float* __restrict__ Mp,
                 const float* __restrict__ Lp, u16* __restrict__ AV)
{
    __shared__ float w1s[64], w2s[64];

    const int tile = blockIdx.x;
    const int bh   = tile & 31;
    const int qb   = 31 - (tile >> 5);          // must match flash mapping
    const int b = bh >> 4, h = bh & 15;
    const int tid = threadIdx.x;
    const size_t t0 = (size_t)tile * 2;

    if (tid < 64) {
        const float m1 = Mp[t0 * 64 + tid], m2 = Mp[(t0 + 1) * 64 + tid];
        const float l1 = Lp[t0 * 64 + tid], l2 = Lp[(t0 + 1) * 64 + tid];
        const float m  = fmaxf(m1, m2);
        const float e1 = exp2f(m1 - m), e2 = exp2f(m2 - m);
        const float inv = 1.0f / (l1 * e1 + l2 * e2);    // l1 > 0 always
        w1s[tid] = l1 * e1 * inv;
        w2s[tid] = l2 * e2 * inv;
    }
    __syncthreads();

    const float* O1 = Ou + t0 * 4096;
    const float* O2 = O1 + 4096;
#pragma unroll
    for (int e = 0; e < 4; ++e) {
        const int elem = e * 1024 + tid * 4;
        const int row  = elem >> 6;
        const int col  = elem & 63;
        const float4 a = *(const float4*)&O1[elem];
        const float4 c = *(const float4*)&O2[elem];
        const float w1 = w1s[row], w2 = w2s[row];
        ushort4 pk;
        pk.x = f2h(a.x * w1 + c.x * w2);
        pk.y = f2h(a.y * w1 + c.y * w2);
        pk.z = f2h(a.z * w1 + c.z * w2);
        pk.w = f2h(a.w * w1 + c.w * w2);
        const int qrow = qb * 64 + row;
        *(ushort4*)&AV[((size_t)qrow * BB + b) * DMODEL + h * 64 + col] = pk;
    }
}

// ---------------------------------------------------------------------------
extern "C" void kernel_launch(void* const* d_in, const int* in_sizes, int n_in,
                              void* d_out, int out_size, void* d_ws, size_t ws_size,
                              hipStream_t stream)
{
    const float* x      = (const float*)d_in[0];
    const float* qkv_w  = (const float*)d_in[1];
    const float* qkv_b  = (const float*)d_in[2];
    const float* out_w  = (const float*)d_in[3];
    const float* out_b  = (const float*)d_in[4];
    const int*   is_causal = (const int*)d_in[5];
    float* out = (float*)d_out;

    u16* ws   = (u16*)d_ws;
    u16* xb   = ws;                       // 4096*1024
    u16* wqkv = xb   + (size_t)4194304;   // 3072*1024
    u16* wout = wqkv + (size_t)3145728;   // 1024*1024
    u16* Qh   = wout + (size_t)1048576;   // [b][h][t][d]
    u16* Kh   = Qh   + (size_t)4194304;   // [b][h][t][d]
    u16* Vth  = Kh   + (size_t)4194304;   // [b][h][d][t]
    u16* AVh  = Vth  + (size_t)4194304;   // 4096*1024
    float* Oup = (float*)(AVh + (size_t)4194304);  // 2048*4096 fp32 partials
    float* Mpp = Oup + (size_t)8388608;            // 2048*64
    float* Lpp = Mpp + (size_t)131072;             // 2048*64

    cast3_f32_f16<<<8192, 256, 0, stream>>>(x, xb, qkv_w, wqkv, out_w, wout);

    // QKV projection: M=4096, N=3072, K=1024 (Q scaled, V transposed)
    gemm_qkv<<<dim3(3 * DMODEL / 128, MROWS / 128), 512, 0, stream>>>(
        xb, wqkv, qkv_b, Qh, Kh, Vth, MROWS, 3 * DMODEL, DMODEL);

    // flash attention: split-K, 2048 blocks (2 per (bh,qb) tile), 6/CU + backfill
    flash_f16<<<2048, 256, 0, stream>>>(Qh, Kh, Vth, Oup, Mpp, Lpp, is_causal);
    flash_merge<<<1024, 256, 0, stream>>>(Oup, Mpp, Lpp, AVh);

    // output projection: M=4096, N=1024, K=1024, 64x64 tiles, BK=128
    gemm_out64<<<dim3(DMODEL / 64, MROWS / 64), 256, 0, stream>>>(
        AVh, wout, out_b, out, MROWS, DMODEL, DMODEL);
}

// Round 13
// 182.553 us; speedup vs baseline: 2.0888x; 2.0888x over previous
//
#include <hip/hip_runtime.h>
#include <math.h>

#define TSEQ   2048
#define BB     2
#define DMODEL 1024
#define NHEAD  16
#define DHEAD  64
#define MROWS  (TSEQ * BB)   // 4096

typedef __attribute__((ext_vector_type(8))) _Float16 half8;
typedef __attribute__((ext_vector_type(4))) float    floatx4;
typedef unsigned short u16;
typedef unsigned int   u32;

#define QSCL 11.5415603f   /* 8 * log2(e): Q pre-scale -> exp2-domain scores */
#define MSK  1442695.0f    /* 1e6 * log2(e) */

__device__ __forceinline__ u16 f2h(float f) {
    union { _Float16 h; u16 u; } cv;
    cv.h = (_Float16)f;
    return cv.u;
}

// packed fp32x2 -> fp16x2 (round-to-zero) as u32
__device__ __forceinline__ u32 pkrtz(float a, float b) {
    typedef __attribute__((ext_vector_type(2))) __fp16 fp16x2;
    union { fp16x2 h; u32 u; } cv;
    cv.h = __builtin_amdgcn_cvt_pkrtz(a, b);
    return cv.u;
}

__device__ __forceinline__ void async_cp16(const u16* g, u16* l) {
    __builtin_amdgcn_global_load_lds(
        (const __attribute__((address_space(1))) unsigned int*)g,
        (__attribute__((address_space(3))) unsigned int*)l, 16, 0, 0);
}

// ---------------------------------------------------------------------------
// one-launch fp32 -> fp16 cast of x, qkv_w, out_w
// ---------------------------------------------------------------------------
__global__ __launch_bounds__(256)
void cast3_f32_f16(const float* __restrict__ a, u16* __restrict__ oa,
                   const float* __restrict__ b, u16* __restrict__ ob,
                   const float* __restrict__ c, u16* __restrict__ oc)
{
    int i = blockIdx.x * 256 + threadIdx.x;
    const float* src; u16* dst; int off;
    if (i < 1048576)      { src = a; dst = oa; off = 0; }
    else if (i < 1835008) { src = b; dst = ob; off = 1048576; }
    else                  { src = c; dst = oc; off = 1835008; }
    int j = i - off;
    float4 v = ((const float4*)src)[j];
    ushort4 o;
    o.x = f2h(v.x); o.y = f2h(v.y); o.z = f2h(v.z); o.w = f2h(v.w);
    ((ushort4*)dst)[j] = o;
}

// ---------------------------------------------------------------------------
// QKV GEMM: 128x128 tile, BK=64, 8 waves; per-wave profile = proven 128x64
// kernel (acc[2][4], 16 MFMA/K-step); 24 waves/CU.  (round-11: 46.0 us)
// ---------------------------------------------------------------------------
__global__ __launch_bounds__(512)
void gemm_qkv(const u16* __restrict__ A, const u16* __restrict__ W,
              const float* __restrict__ bias,
              u16* __restrict__ Qo, u16* __restrict__ Ko, u16* __restrict__ Vo,
              int M, int N, int K)
{
    __shared__ __align__(16) u16 As[128][64];
    __shared__ __align__(16) u16 Bs[128][64];

    const int tid  = threadIdx.x;
    const int lane = tid & 63;
    const int wv   = tid >> 6;               // 0..7
    const int wr   = wv >> 1;                // 0..3: 32-row band
    const int wc   = wv & 1;                 // 0..1: 64-col half
    const int ln   = lane & 15, lh = lane >> 4;
    const int m0   = blockIdx.y * 128;
    const int n0   = blockIdx.x * 128;

    const int c = n0 >> 10;                  // 0,1,2 = q,k,v (block-uniform)
    const bool vmode = (c == 2);             // normal orientation

    const floatx4 zero4 = {0.0f, 0.0f, 0.0f, 0.0f};
    floatx4 acc[2][4];
#pragma unroll
    for (int i = 0; i < 2; ++i)
#pragma unroll
        for (int j = 0; j < 4; ++j) acc[i][j] = zero4;

    for (int k0 = 0; k0 < K; k0 += 64) {
        __syncthreads();
#pragma unroll
        for (int t = 0; t < 2; ++t) {
            const int u    = t * 512 + tid;
            const int row  = u >> 3;
            const int slot = u & 7;
            const int g    = slot ^ (row & 7);
            async_cp16(A + (size_t)(m0 + row) * K + k0 + g * 8, &As[row][slot * 8]);
            async_cp16(W + (size_t)(n0 + row) * K + k0 + g * 8, &Bs[row][slot * 8]);
        }
        __syncthreads();

#pragma unroll
        for (int ks = 0; ks < 2; ++ks) {
            half8 xf[2], wf[4];
#pragma unroll
            for (int i = 0; i < 2; ++i) {
                const int row = wr * 32 + i * 16 + ln;
                xf[i] = *(const half8*)&As[row][(((ks << 2) | lh) ^ (row & 7)) * 8];
            }
#pragma unroll
            for (int j = 0; j < 4; ++j) {
                const int row = wc * 64 + j * 16 + ln;
                wf[j] = *(const half8*)&Bs[row][(((ks << 2) | lh) ^ (row & 7)) * 8];
            }
            if (vmode) {
#pragma unroll
                for (int i = 0; i < 2; ++i)
#pragma unroll
                    for (int j = 0; j < 4; ++j)
                        acc[i][j] = __builtin_amdgcn_mfma_f32_16x16x32_f16(xf[i], wf[j], acc[i][j], 0, 0, 0);
            } else {
#pragma unroll
                for (int i = 0; i < 2; ++i)
#pragma unroll
                    for (int j = 0; j < 4; ++j)
                        acc[i][j] = __builtin_amdgcn_mfma_f32_16x16x32_f16(wf[j], xf[i], acc[i][j], 0, 0, 0);
            }
        }
    }

    if (!vmode) {
        const float scl = (c == 0) ? QSCL : 1.0f;
        u16* dst = (c == 0) ? Qo : Ko;
#pragma unroll
        for (int j = 0; j < 4; ++j) {
            const int nb = n0 + wc * 64 + j * 16 + lh * 4;
            const float4 b4 = *(const float4*)&bias[nb];
            const int h  = (nb >> 6) & 15;
            const int d0 = nb & 63;
#pragma unroll
            for (int i = 0; i < 2; ++i) {
                const int tok = m0 + wr * 32 + i * 16 + ln;
                const int t = tok >> 1, b = tok & 1;
                uint2 pk;
                pk.x = pkrtz((acc[i][j][0] + b4.x) * scl, (acc[i][j][1] + b4.y) * scl);
                pk.y = pkrtz((acc[i][j][2] + b4.z) * scl, (acc[i][j][3] + b4.w) * scl);
                *(uint2*)&dst[(((size_t)b * NHEAD + h) * TSEQ + t) * DHEAD + d0] = pk;
            }
        }
    } else {
#pragma unroll
        for (int j = 0; j < 4; ++j) {
            const int col = n0 + wc * 64 + j * 16 + ln;
            const float bc = bias[col];
            const int h = (col >> 6) & 15;
            const int d = col & 63;
#pragma unroll
            for (int i = 0; i < 2; ++i) {
                const int mb = m0 + wr * 32 + i * 16 + lh * 4;
                const int t0 = mb >> 1;
                const u32 e0 = pkrtz(acc[i][j][0] + bc, acc[i][j][2] + bc);  // b=0
                const u32 e1 = pkrtz(acc[i][j][1] + bc, acc[i][j][3] + bc);  // b=1
                *(u32*)&Vo[(((size_t)0 * NHEAD + h) * DHEAD + d) * TSEQ + t0] = e0;
                *(u32*)&Vo[(((size_t)1 * NHEAD + h) * DHEAD + d) * TSEQ + t0] = e1;
            }
        }
    }
}

// ---------------------------------------------------------------------------
// out-proj GEMM: 64x64 tile, BK=128; XCD swizzle. (round-8 verified ~26 us)
// ---------------------------------------------------------------------------
__global__ __launch_bounds__(256)
void gemm_out64(const u16* __restrict__ A, const u16* __restrict__ W,
                const float* __restrict__ bias, float* __restrict__ Cout,
                int M, int N, int K)
{
    __shared__ __align__(16) u16 As[64][128];
    __shared__ __align__(16) u16 Bs[64][128];

    const int tid  = threadIdx.x;
    const int lane = tid & 63;
    const int wv   = tid >> 6;
    const int ln   = lane & 15, lh = lane >> 4;

    const int bidlin = blockIdx.y * 16 + blockIdx.x;
    const int wg  = (bidlin & 7) * 128 + (bidlin >> 3);
    const int bx  = wg & 15, by = wg >> 4;
    const int m0  = by * 64;
    const int n0  = bx * 64;

    const floatx4 zero4 = {0.0f, 0.0f, 0.0f, 0.0f};
    floatx4 acc[4];
#pragma unroll
    for (int j = 0; j < 4; ++j) acc[j] = zero4;

    for (int k0 = 0; k0 < K; k0 += 128) {
        __syncthreads();
#pragma unroll
        for (int u = 0; u < 4; ++u) {
            const int idx  = u * 256 + tid;
            const int row  = idx >> 4;
            const int slot = idx & 15;
            const int g    = (slot & 8) | ((slot & 7) ^ (row & 7));
            async_cp16(A + (size_t)(m0 + row) * K + k0 + g * 8, &As[row][slot * 8]);
            async_cp16(W + (size_t)(n0 + row) * K + k0 + g * 8, &Bs[row][slot * 8]);
        }
        __syncthreads();

#pragma unroll
        for (int ks = 0; ks < 4; ++ks) {
            const int arow = wv * 16 + ln;
            half8 xf = *(const half8*)&As[arow][(((ks << 2) | lh) ^ (arow & 7)) * 8];
#pragma unroll
            for (int j = 0; j < 4; ++j) {
                const int row = j * 16 + ln;
                half8 wf = *(const half8*)&Bs[row][(((ks << 2) | lh) ^ (row & 7)) * 8];
                acc[j] = __builtin_amdgcn_mfma_f32_16x16x32_f16(wf, xf, acc[j], 0, 0, 0);
            }
        }
    }

#pragma unroll
    for (int j = 0; j < 4; ++j) {
        const int fb = n0 + j * 16 + lh * 4;
        const float4 b4 = *(const float4*)&bias[fb];
        const int tok = m0 + wv * 16 + ln;
        float4 v;
        v.x = acc[j][0] + b4.x;
        v.y = acc[j][1] + b4.y;
        v.z = acc[j][2] + b4.z;
        v.w = acc[j][3] + b4.w;
        *(float4*)&Cout[(size_t)tok * N + fb] = v;
    }
}

// ---------------------------------------------------------------------------
// S^T-formulation MFMA flash attention, 64-q-row tiles, one tile per block.
// (round-11 proven version, 183.98 us total.)  Round-12's split-K variant
// REVERTED: __launch_bounds__(256,6) capped VGPRs below need -> spill to
// scratch (VGPR 64->40, WRITE_SIZE 8MB->654MB, MfmaUtil 3%) -> HBM-bound at
// 57% peak, 235us. Lesson: a VGPR count that DROPS while memory traffic
// explodes = spill; never raise min-waves without re-checking VGPR fit.
// Keeps: unpadded [64]-u16 rows + 16B-granule XOR swizzle on writes AND
// reads (0-conflict scheme), defer-max, reg ones-frag l_i, direct-global Q,
// early V ds_reads, setprio, 4-phase causal balance.
// ---------------------------------------------------------------------------
__global__ __launch_bounds__(256, 4)
void flash_f16(const u16* __restrict__ Q, const u16* __restrict__ K,
               const u16* __restrict__ Vt, u16* __restrict__ AV,
               const int* __restrict__ causal_p)
{
    // rows 0..63 = P; 64..127 = K; 128..191 = V^T   (24.6 KB, no pad)
    __shared__ __align__(16) u16 smem[192 * 64];
    u16 (* __restrict__ Ps)[64] = (u16(*)[64])smem;
    u16 (* __restrict__ Ks)[64] = (u16(*)[64])(smem + 64 * 64);
    u16 (* __restrict__ Vs)[64] = (u16(*)[64])(smem + 128 * 64);

    const int tid  = threadIdx.x;
    const int lane = tid & 63;
    const int wv   = tid >> 6;
    const int ln   = lane & 15, lh = lane >> 4;

    const int phase = blockIdx.x >> 8;          // 0..3
    const int slot  = blockIdx.x & 255;
    const int bh    = slot & 31;                // b*16 + h
    const int jq    = slot >> 5;                // 0..7
    int qb;
    if      (phase == 0) qb = 31 - jq;
    else if (phase == 1) qb = jq;
    else if (phase == 2) qb = 23 - jq;
    else                 qb = 8 + jq;

    const int b = bh >> 4;
    const int h = bh & 15;
    const int causal = causal_p[0];

    const u16* Qg = Q  + (size_t)bh * TSEQ * DHEAD;
    const u16* Kg = K  + (size_t)bh * TSEQ * DHEAD;
    const u16* Vg = Vt + (size_t)bh * DHEAD * TSEQ;

    const int lrow = tid >> 3;                  // 0..31
    const int lc8  = (tid & 7) * 8;             // global col (linear)
    const int lg8  = ((tid & 7) ^ (lrow & 7)) * 8;   // LDS col (swizzled)

    const int qr0   = wv * 16;
    const int qloc  = qr0 + ln;                 // this lane's q-row (local)
    const int s7    = ln & 7;                   // row&7 for all frag rows
    const int qglob = qb * 64 + qloc;

    // Q B-frags straight from global (read once)
    const half8 bQ0 = *(const half8*)(Qg + (size_t)qglob * DHEAD + lh * 8);
    const half8 bQ1 = *(const half8*)(Qg + (size_t)qglob * DHEAD + 32 + lh * 8);

    // ones B-frag: B[k][col] = (col==0) -> lanes with ln==0 hold 1.0
    const _Float16 ov = (_Float16)((ln == 0) ? 1.0f : 0.0f);
    const half8 ones = {ov, ov, ov, ov, ov, ov, ov, ov};

    const floatx4 zero4 = {0.0f, 0.0f, 0.0f, 0.0f};
    floatx4 o[4], o4;
#pragma unroll
    for (int j = 0; j < 4; ++j) o[j] = zero4;
    o4 = zero4;
    float m_i = -3.0e38f;

    const int kb_end = causal ? qb : (TSEQ / 64 - 1);

    // prologue: prefetch K/V^T block 0 into regs
    uint4 kreg0 = *(const uint4*)(Kg + (size_t)lrow * DHEAD + lc8);
    uint4 kreg1 = *(const uint4*)(Kg + (size_t)(lrow + 32) * DHEAD + lc8);
    uint4 vreg0 = *(const uint4*)(Vg + (size_t)lrow * TSEQ + lc8);
    uint4 vreg1 = *(const uint4*)(Vg + (size_t)(lrow + 32) * TSEQ + lc8);

    for (int kb = 0; kb <= kb_end; ++kb) {
        // stage prefetched regs -> LDS (swizzled dest; (lrow+32)&7 == lrow&7)
        *(uint4*)&Ks[lrow][lg8]      = kreg0;
        *(uint4*)&Ks[lrow + 32][lg8] = kreg1;
        *(uint4*)&Vs[lrow][lg8]      = vreg0;
        *(uint4*)&Vs[lrow + 32][lg8] = vreg1;
        __syncthreads();

        // prefetch next K/V^T block (hidden behind compute)
        if (kb < kb_end) {
            const size_t nk = (size_t)(kb + 1) * 64;
            kreg0 = *(const uint4*)(Kg + (nk + lrow) * DHEAD + lc8);
            kreg1 = *(const uint4*)(Kg + (nk + lrow + 32) * DHEAD + lc8);
            vreg0 = *(const uint4*)(Vg + (size_t)lrow * TSEQ + nk + lc8);
            vreg1 = *(const uint4*)(Vg + (size_t)(lrow + 32) * TSEQ + nk + lc8);
        }

        // S^T = K Q^T : s[j][r] = S[key = 16j+4lh+r][q = qloc]
        floatx4 s[4];
        __builtin_amdgcn_s_setprio(1);
#pragma unroll
        for (int j = 0; j < 4; ++j) {
            half8 aK0 = *(const half8*)&Ks[j * 16 + ln][(lh ^ s7) * 8];
            half8 aK1 = *(const half8*)&Ks[j * 16 + ln][((4 | lh) ^ s7) * 8];
            floatx4 z = zero4;
            z = __builtin_amdgcn_mfma_f32_16x16x32_f16(aK0, bQ0, z, 0, 0, 0);
            z = __builtin_amdgcn_mfma_f32_16x16x32_f16(aK1, bQ1, z, 0, 0, 0);
            s[j] = z;
        }
        __builtin_amdgcn_s_setprio(0);

        // V frags early: LDS latency hides under the softmax VALU burst
        half8 bV[8];
#pragma unroll
        for (int j = 0; j < 4; ++j) {
            bV[2 * j]     = *(const half8*)&Vs[j * 16 + ln][(lh ^ s7) * 8];
            bV[2 * j + 1] = *(const half8*)&Vs[j * 16 + ln][((4 | lh) ^ s7) * 8];
        }

        // causal mask: only the diagonal tile needs it
        if ((causal != 0) && (kb == qb)) {
#pragma unroll
            for (int j = 0; j < 4; ++j)
#pragma unroll
                for (int r = 0; r < 4; ++r)
                    if (j * 16 + lh * 4 + r > qloc) s[j][r] -= MSK;
        }

        // per-lane online max (one q-row per lane; reduce across lh groups)
        float mx = m_i;
#pragma unroll
        for (int j = 0; j < 4; ++j)
#pragma unroll
            for (int r = 0; r < 4; ++r) mx = fmaxf(mx, s[j][r]);
        mx = fmaxf(mx, __shfl_xor(mx, 16));
        mx = fmaxf(mx, __shfl_xor(mx, 32));

        // defer-max: rescale only when the max moved by >8 exp2-units
        if (!__all(mx <= m_i + 8.0f)) {
            const float alpha = exp2f(m_i - mx);
            m_i = mx;
            float a_r[4];
#pragma unroll
            for (int r = 0; r < 4; ++r) a_r[r] = __shfl(alpha, lh * 4 + r);
#pragma unroll
            for (int j = 0; j < 4; ++j)
#pragma unroll
                for (int r = 0; r < 4; ++r) o[j][r] *= a_r[r];
#pragma unroll
            for (int r = 0; r < 4; ++r) o4[r] *= a_r[r];
        }

        // P = exp2(s - m_i), packed to LDS (swizzled: granule 2j+(lh>>1),
        // sub-offset (lh&1)*4 u16 -- same row-XOR as the reads)
#pragma unroll
        for (int j = 0; j < 4; ++j) {
            uint2 pk;
            pk.x = pkrtz(exp2f(s[j][0] - m_i), exp2f(s[j][1] - m_i));
            pk.y = pkrtz(exp2f(s[j][2] - m_i), exp2f(s[j][3] - m_i));
            *(uint2*)&Ps[qloc][(((2 * j + (lh >> 1)) ^ s7) * 8) + (lh & 1) * 4] = pk;
        }

        // O += P V ; o4 += P * ones (row-sums -> l_i recurrence for free)
        half8 aP0 = *(const half8*)&Ps[qloc][(lh ^ s7) * 8];
        half8 aP1 = *(const half8*)&Ps[qloc][((4 | lh) ^ s7) * 8];
        __builtin_amdgcn_s_setprio(1);
#pragma unroll
        for (int j = 0; j < 4; ++j) {
            o[j] = __builtin_amdgcn_mfma_f32_16x16x32_f16(aP0, bV[2 * j],     o[j], 0, 0, 0);
            o[j] = __builtin_amdgcn_mfma_f32_16x16x32_f16(aP1, bV[2 * j + 1], o[j], 0, 0, 0);
        }
        o4 = __builtin_amdgcn_mfma_f32_16x16x32_f16(aP0, ones, o4, 0, 0, 0);
        o4 = __builtin_amdgcn_mfma_f32_16x16x32_f16(aP1, ones, o4, 0, 0, 0);
        __builtin_amdgcn_s_setprio(0);

        __syncthreads();   // all reads of Ks/Vs/Ps done before next staging
    }

    // epilogue: o rows = q-local lh*4+r, cols d = 16j+ln.
    // l of q-row 4lh'+r lives in o4[r] of lane 16*lh' (column d=0 -> ln=0).
#pragma unroll
    for (int r = 0; r < 4; ++r) {
        const float lr = __shfl(o4[r], lane & 48);
        const float il = 1.0f / lr;
        const int qrow = qb * 64 + qr0 + lh * 4 + r;
#pragma unroll
        for (int j = 0; j < 4; ++j) {
            const int d = j * 16 + ln;
            AV[((size_t)qrow * BB + b) * DMODEL + h * 64 + d] = f2h(o[j][r] * il);
        }
    }
}

// ---------------------------------------------------------------------------
extern "C" void kernel_launch(void* const* d_in, const int* in_sizes, int n_in,
                              void* d_out, int out_size, void* d_ws, size_t ws_size,
                              hipStream_t stream)
{
    const float* x      = (const float*)d_in[0];
    const float* qkv_w  = (const float*)d_in[1];
    const float* qkv_b  = (const float*)d_in[2];
    const float* out_w  = (const float*)d_in[3];
    const float* out_b  = (const float*)d_in[4];
    const int*   is_causal = (const int*)d_in[5];
    float* out = (float*)d_out;

    u16* ws   = (u16*)d_ws;
    u16* xb   = ws;                       // 4096*1024
    u16* wqkv = xb   + (size_t)4194304;   // 3072*1024
    u16* wout = wqkv + (size_t)3145728;   // 1024*1024
    u16* Qh   = wout + (size_t)1048576;   // [b][h][t][d]
    u16* Kh   = Qh   + (size_t)4194304;   // [b][h][t][d]
    u16* Vth  = Kh   + (size_t)4194304;   // [b][h][d][t]
    u16* AVh  = Vth  + (size_t)4194304;   // 4096*1024

    cast3_f32_f16<<<8192, 256, 0, stream>>>(x, xb, qkv_w, wqkv, out_w, wout);

    // QKV projection: M=4096, N=3072, K=1024 (Q scaled, V transposed)
    gemm_qkv<<<dim3(3 * DMODEL / 128, MROWS / 128), 512, 0, stream>>>(
        xb, wqkv, qkv_b, Qh, Kh, Vth, MROWS, 3 * DMODEL, DMODEL);

    // flash attention: 1024 blocks, one 64-row q-tile each, 4 resident/CU
    flash_f16<<<1024, 256, 0, stream>>>(Qh, Kh, Vth, AVh, is_causal);

    // output projection: M=4096, N=1024, K=1024, 64x64 tiles, BK=128
    gemm_out64<<<dim3(DMODEL / 64, MROWS / 64), 256, 0, stream>>>(
        AVh, wout, out_b, out, MROWS, DMODEL, DMODEL);
}